// Round 4
// baseline (113.861 us; speedup 1.0000x reference)
//
#include <hip/hip_runtime.h>
#include <hip/hip_bf16.h>

// PRNN R4: GRU(NH=128, T=32) + MLP head, B=16384.
// 8 waves / 32-seq tile, grid=512. One barrier per step: lds_h & lds_hid double-
// buffered on t&1, P5 (logits of step t-1) deferred past B1(t), split over 2 waves.
// exp2-domain prescale: Ar/Az/xrz *= log2e; An/xn/bhn *= 2*log2e -> sigmoid/tanh
// have no argument multiplies. b_hh_n/b1/b2 C-inits in registers.

#define NSTEP 32
#define BT    32
#define BLK   512

using s8v = __attribute__((ext_vector_type(8))) short;   // 8 bf16
using f4v = __attribute__((ext_vector_type(4))) float;   // MFMA acc

#define L2E 1.4426950408889634f
#define LN2 0.6931471805599453f

__device__ __forceinline__ unsigned short f2bf(float f) {
  __hip_bfloat16 h = __float2bfloat16(f);
  return __builtin_bit_cast(unsigned short, h);
}
__device__ __forceinline__ unsigned pkbf2(float a, float b) {
  return (unsigned)f2bf(a) | ((unsigned)f2bf(b) << 16);
}
__device__ __forceinline__ s8v pack8s(float sc, float4 u, float4 v) {
  s8v a;
  a[0]=(short)f2bf(sc*u.x); a[1]=(short)f2bf(sc*u.y); a[2]=(short)f2bf(sc*u.z); a[3]=(short)f2bf(sc*u.w);
  a[4]=(short)f2bf(sc*v.x); a[5]=(short)f2bf(sc*v.y); a[6]=(short)f2bf(sc*v.z); a[7]=(short)f2bf(sc*v.w);
  return a;
}
__device__ __forceinline__ f4v mfma16(s8v a, s8v b, f4v c) {
  return __builtin_amdgcn_mfma_f32_16x16x32_bf16(a, b, c, 0, 0, 0);
}
// inputs pre-scaled to exp2 domain
__device__ __forceinline__ float sigm2(float x) {
  return __builtin_amdgcn_rcpf(1.f + __builtin_amdgcn_exp2f(-x));
}
__device__ __forceinline__ float tanh2(float x) {
  return __builtin_fmaf(2.f, __builtin_amdgcn_rcpf(1.f + __builtin_amdgcn_exp2f(-x)), -1.f);
}

__global__ __launch_bounds__(BLK, 4) void prnn_kernel(
    const float* __restrict__ x, const float* __restrict__ w_ih,
    const float* __restrict__ w_hh, const float* __restrict__ b_ih,
    const float* __restrict__ b_hh, const float* __restrict__ w1,
    const float* __restrict__ b1, const float* __restrict__ w2,
    const float* __restrict__ b2, float* __restrict__ out) {

  __shared__ __align__(16) unsigned char lds_h[2][8192];       // 16 KB h B-frags (dbuf)
  __shared__ __align__(16) unsigned char lds_hid[2][8192];     // 16 KB hid B-frags (dbuf)
  __shared__ __align__(16) unsigned char lds_wA1[8*4*64*16];   // 32 KB w1 A-frags
  __shared__ __align__(16) unsigned char lds_w2f[4*64*16];     // 4 KB  w2 A-frags
  __shared__ __align__(16) float lds_xrz[64*4*4];              // 4 KB  xi r,z (*L2E)
  __shared__ __align__(16) float lds_xn[32*4*4];               // 2 KB  xi n (*2L2E)
  __shared__ unsigned lds_idx[32*8];                           // 1 KB
  __shared__ float lds_lp[8][32];                              // 1 KB

  const int tid = threadIdx.x;
  const int bbase = blockIdx.x * BT;
  const int lane = tid & 63;
  const int lg = lane >> 4, ln = lane & 15;
  const int w = __builtin_amdgcn_readfirstlane(tid >> 6);   // wave 0..7

  // ---- init: patch indices ----
  if (tid < 256) {
    int b = tid >> 3, ch = tid & 7;
    const float* xp = x + (size_t)(bbase + b) * 64 + ch * 8;
    float4 v0 = *(const float4*)xp, v1 = *(const float4*)(xp + 4);
    unsigned pk = ((v0.x!=0.f?1u:0u) | (v0.y!=0.f?2u:0u))
               | (((v0.z!=0.f?1u:0u) | (v0.w!=0.f?2u:0u)) << 8)
               | (((v1.x!=0.f?1u:0u) | (v1.y!=0.f?2u:0u)) << 16)
               | (((v1.z!=0.f?1u:0u) | (v1.w!=0.f?2u:0u)) << 24);
    lds_idx[b*8 + ch] = pk;
  }
  // ---- init: xi tables (prescaled) ----
  if (tid < 256) {                              // rows 0..255 (r,z) * L2E
    int j = tid;
    float base = b_ih[j] + b_hh[j];
    float wa = w_ih[2*j], wb = w_ih[2*j+1];
    int q = j >> 2, e = j & 3;
    #pragma unroll
    for (int v = 0; v < 4; ++v)
      lds_xrz[(q*4+v)*4 + e] = L2E * (base + ((v&1) ? wa : 0.f) + ((v&2) ? wb : 0.f));
  }
  if (tid < 128) {                              // rows 256..383 (n) * 2L2E
    int j2 = 256 + tid;
    float bn = b_ih[j2];
    float wan = w_ih[2*j2], wbn = w_ih[2*j2+1];
    int qn = tid >> 2, en = tid & 3;
    #pragma unroll
    for (int v = 0; v < 4; ++v)
      lds_xn[(qn*4+v)*4 + en] = (2.f*L2E) * (bn + ((v&1) ? wan : 0.f) + ((v&2) ? wbn : 0.f));
  }
  // ---- init: w1 A-frags (unscaled), fragment order ----
  #pragma unroll
  for (int it = 0; it < 4; ++it) {
    int i = tid + it * BLK;                     // 0..2047
    int mt = i >> 8, ks = (i >> 6) & 3, l = i & 63;
    const float* src = w1 + (16*mt + (l & 15)) * 128 + ks*32 + (l >> 4)*8;
    *(s8v*)(lds_wA1 + ((mt*4 + ks)*64 + l)*16) = pack8s(1.f, *(const float4*)src, *(const float4*)(src+4));
  }
  // ---- init: w2 A-frags ----
  if (tid < 256) {
    int ks = tid >> 6, l = tid & 63;
    s8v fr;
    #pragma unroll
    for (int e = 0; e < 8; ++e) fr[e] = (short)0;
    if ((l & 15) < 4) {
      const float* src = w2 + (l & 15) * 128 + ks*32 + (l >> 4)*8;
      fr = pack8s(1.f, *(const float4*)src, *(const float4*)(src + 4));
    }
    *(s8v*)(lds_w2f + (ks*64 + l)*16) = fr;
  }

  // ---- register weights: w_hh A-frags (prescaled) ----
  s8v Ar[4], Az[4], An[4];
  {
    const int row = 16*w + ln;
    #pragma unroll
    for (int ks = 0; ks < 4; ++ks) {
      const float* s0 = w_hh + row*128 + ks*32 + lg*8;
      Ar[ks] = pack8s(L2E, *(const float4*)s0, *(const float4*)(s0 + 4));
      const float* s1 = s0 + 128*128;
      Az[ks] = pack8s(L2E, *(const float4*)s1, *(const float4*)(s1 + 4));
      const float* s2 = s0 + 256*128;
      An[ks] = pack8s(2.f*L2E, *(const float4*)s2, *(const float4*)(s2 + 4));
    }
  }
  // ---- register biases ----
  const int q = 4*w + lg;
  f4v bhnr, b1i, b2r;
  {
    const f4v bh = *(const f4v*)(b_hh + 256 + q*4);
    bhnr[0]=(2.f*L2E)*bh[0]; bhnr[1]=(2.f*L2E)*bh[1]; bhnr[2]=(2.f*L2E)*bh[2]; bhnr[3]=(2.f*L2E)*bh[3];
    b1i = *(const f4v*)(b1 + q*4);
    if (lg == 0) b2r = *(const f4v*)b2;
    else { b2r[0]=0.f; b2r[1]=0.f; b2r[2]=0.f; b2r[3]=0.f; }
  }

  __syncthreads();

  // ---- per-lane packed patch history (cols ln, 16+ln) ----
  unsigned pk0a=0, pk0b=0, pk1a=0, pk1b=0;
  #pragma unroll
  for (int w8 = 0; w8 < 4; ++w8) {
    unsigned u = lds_idx[ln*8 + w8];
    pk0a |= (((u&3u) | ((u>>6)&0xCu) | ((u>>12)&0x30u) | ((u>>18)&0xC0u)) << (8*w8));
    unsigned u2 = lds_idx[(16+ln)*8 + w8];
    pk1a |= (((u2&3u) | ((u2>>6)&0xCu) | ((u2>>12)&0x30u) | ((u2>>18)&0xC0u)) << (8*w8));
  }
  #pragma unroll
  for (int w8 = 4; w8 < 8; ++w8) {
    unsigned u = lds_idx[ln*8 + w8];
    pk0b |= (((u&3u) | ((u>>6)&0xCu) | ((u>>12)&0x30u) | ((u>>18)&0xC0u)) << (8*(w8-4)));
    unsigned u2 = lds_idx[(16+ln)*8 + w8];
    pk1b |= (((u2&3u) | ((u2>>6)&0xCu) | ((u2>>12)&0x30u) | ((u2>>18)&0xC0u)) << (8*(w8-4)));
  }

  const unsigned wroff = (unsigned)((((w>>1)*128) + 16*(2*(w&1) + (lg>>1)) + ln)*16 + 8*(lg&1));

  s8v Bf[4][2];
  #pragma unroll
  for (int ks = 0; ks < 4; ++ks)
    #pragma unroll
    for (int nt = 0; nt < 2; ++nt)
      #pragma unroll
      for (int e = 0; e < 8; ++e) Bf[ks][nt][e] = (short)0;
  f4v hfr[2];
  hfr[0][0]=0.f; hfr[0][1]=0.f; hfr[0][2]=0.f; hfr[0][3]=0.f;
  hfr[1] = hfr[0];
  float lp0 = 0.f, lp1 = 0.f;
  int pv0 = 0, pv1 = 0;

  // P5 body: logits + log-softmax gather for step u (one nt half)
  auto do_p5 = [&](int u, int uslot) {
    const int ua = u & 7;
    const bool d0 = (w == ua), d1 = (w == (ua ^ 4));
    if (d0 | d1) {
      const int ntx = d1 ? 1 : 0;
      f4v la = b2r;
      #pragma unroll
      for (int ks = 0; ks < 4; ++ks) {
        const s8v W2f = *(const s8v*)(lds_w2f + (ks*64 + lane)*16);
        const s8v Bh  = *(const s8v*)(&lds_hid[uslot][((ks*2 + ntx)*64 + lane)*16]);
        la = mfma16(W2f, Bh, la);
      }
      if (lg == 0) {
        const unsigned hsel = ntx ? ((u & 16) ? pk1b : pk1a) : ((u & 16) ? pk0b : pk0a);
        const int ic = (int)((hsel >> ((2*u) & 31)) & 3);
        float l0=la[0], l1=la[1], l2=la[2], l3=la[3];
        float m = fmaxf(fmaxf(l0, l1), fmaxf(l2, l3));
        float s = __builtin_amdgcn_exp2f((l0-m)*L2E) + __builtin_amdgcn_exp2f((l1-m)*L2E)
                + __builtin_amdgcn_exp2f((l2-m)*L2E) + __builtin_amdgcn_exp2f((l3-m)*L2E);
        float sel = (ic == 0) ? l0 : (ic == 1) ? l1 : (ic == 2) ? l2 : l3;
        float v = (sel - m) - __builtin_amdgcn_logf(s) * LN2;
        if (ntx) lp1 += v; else lp0 += v;
      }
    }
  };

  for (int tb = 0; tb < NSTEP; tb += 8) {
    #pragma unroll
    for (int k = 0; k < 8; ++k) {
      const int t = tb + k;
      const int slot = t & 1;
      // ---- P1: gate MFMAs (C-init = prescaled xi) + gates + h write ----
      #pragma unroll
      for (int nt = 0; nt < 2; ++nt) {
        const int var = nt ? pv1 : pv0;
        f4v aR = *(const f4v*)&lds_xrz[(q*4 + var)*4];
        f4v aZ = *(const f4v*)&lds_xrz[((q+32)*4 + var)*4];
        f4v aN = bhnr;
        #pragma unroll
        for (int ks = 0; ks < 4; ++ks) {
          aR = mfma16(Ar[ks], Bf[ks][nt], aR);
          aZ = mfma16(Az[ks], Bf[ks][nt], aZ);
          aN = mfma16(An[ks], Bf[ks][nt], aN);
        }
        const f4v xnv = *(const f4v*)&lds_xn[(q*4 + var)*4];
        f4v hn;
        #pragma unroll
        for (int r = 0; r < 4; ++r) {
          float R  = sigm2(aR[r]);
          float Z  = sigm2(aZ[r]);
          float Ng = tanh2(__builtin_fmaf(R, aN[r], xnv[r]));
          hn[r] = __builtin_fmaf(Z, hfr[nt][r] - Ng, Ng);
        }
        hfr[nt] = hn;
        uint2 wv;
        wv.x = pkbf2(hn[0], hn[1]);
        wv.y = pkbf2(hn[2], hn[3]);
        *(uint2*)(&lds_h[slot][wroff + (unsigned)(nt*1024)]) = wv;
      }
      __syncthreads();                           // B1: h(t) complete
      // ---- read Bf (feeds P4 now and P1 of t+1) ----
      #pragma unroll
      for (int ks = 0; ks < 4; ++ks)
        #pragma unroll
        for (int nt = 0; nt < 2; ++nt)
          Bf[ks][nt] = *(const s8v*)(&lds_h[slot][((ks*2 + nt)*64 + lane)*16]);
      // ---- P4: hid = relu(W1 h + b1) -> lds_hid[slot] ----
      f4v hc0 = b1i, hc1 = b1i;
      #pragma unroll
      for (int ks = 0; ks < 4; ++ks) {
        const s8v wf = *(const s8v*)(lds_wA1 + ((w*4 + ks)*64 + lane)*16);
        hc0 = mfma16(wf, Bf[ks][0], hc0);
        hc1 = mfma16(wf, Bf[ks][1], hc1);
      }
      {
        uint2 wv;
        wv.x = pkbf2(fmaxf(hc0[0],0.f), fmaxf(hc0[1],0.f));
        wv.y = pkbf2(fmaxf(hc0[2],0.f), fmaxf(hc0[3],0.f));
        *(uint2*)(&lds_hid[slot][wroff]) = wv;
        wv.x = pkbf2(fmaxf(hc1[0],0.f), fmaxf(hc1[1],0.f));
        wv.y = pkbf2(fmaxf(hc1[2],0.f), fmaxf(hc1[3],0.f));
        *(uint2*)(&lds_hid[slot][wroff + 1024u]) = wv;
      }
      // ---- P5 for step t-1 (reads hid[slot^1], synced by B1 above) ----
      if (t > 0) do_p5(t - 1, slot ^ 1);
      // ---- advance teacher-forcing input ----
      {
        const unsigned g0 = (t & 16) ? pk0b : pk0a;
        const unsigned g1 = (t & 16) ? pk1b : pk1a;
        const int sh = (2*t) & 31;
        pv0 = (int)((g0 >> sh) & 3);
        pv1 = (int)((g1 >> sh) & 3);
      }
    }
  }

  // ---- epilogue: P5 for t=31 ----
  __syncthreads();
  do_p5(NSTEP - 1, (NSTEP - 1) & 1);

  // ---- cross-wave logp reduction ----
  if (lg == 0) { lds_lp[w][ln] = lp0; lds_lp[w][16 + ln] = lp1; }
  __syncthreads();
  if (tid < 32) {
    float s = 0.f;
    #pragma unroll
    for (int ww = 0; ww < 8; ++ww) s += lds_lp[ww][tid];
    out[bbase + tid] = s;
  }
}

extern "C" void kernel_launch(void* const* d_in, const int* in_sizes, int n_in,
                              void* d_out, int out_size, void* d_ws, size_t ws_size,
                              hipStream_t stream) {
  const float* x    = (const float*)d_in[0];
  const float* w_ih = (const float*)d_in[1];
  const float* w_hh = (const float*)d_in[2];
  const float* b_ih = (const float*)d_in[3];
  const float* b_hh = (const float*)d_in[4];
  const float* w1   = (const float*)d_in[5];
  const float* b1   = (const float*)d_in[6];
  const float* w2   = (const float*)d_in[7];
  const float* b2   = (const float*)d_in[8];
  float* out = (float*)d_out;
  int B = in_sizes[0] / 64;          // 16384
  int grid = B / BT;                 // 512
  prnn_kernel<<<grid, BLK, 0, stream>>>(x, w_ih, w_hh, b_ih, b_hh, w1, b1, w2, b2, out);
}

// Round 5
// 109.465 us; speedup vs baseline: 1.0402x; 1.0402x over previous
//
#include <hip/hip_runtime.h>
#include <hip/hip_bf16.h>

// PRNN R5: GRU(NH=128, T=32) + MLP head, B=16384.
// = R4 structure (1 barrier/step, dbuf h/hid, deferred split P5, exp2 prescale)
// + amdgpu_waves_per_eu(4,4): occupancy is LDS-bound at 2 blocks/CU anyway, so
//   give the allocator the full 128-VGPR budget -> no scratch spills (R4's bug).

#define NSTEP 32
#define BT    32
#define BLK   512

using s8v = __attribute__((ext_vector_type(8))) short;   // 8 bf16
using f4v = __attribute__((ext_vector_type(4))) float;   // MFMA acc

#define L2E 1.4426950408889634f
#define LN2 0.6931471805599453f

__device__ __forceinline__ unsigned short f2bf(float f) {
  __hip_bfloat16 h = __float2bfloat16(f);
  return __builtin_bit_cast(unsigned short, h);
}
__device__ __forceinline__ unsigned pkbf2(float a, float b) {
  return (unsigned)f2bf(a) | ((unsigned)f2bf(b) << 16);
}
__device__ __forceinline__ s8v pack8s(float sc, float4 u, float4 v) {
  s8v a;
  a[0]=(short)f2bf(sc*u.x); a[1]=(short)f2bf(sc*u.y); a[2]=(short)f2bf(sc*u.z); a[3]=(short)f2bf(sc*u.w);
  a[4]=(short)f2bf(sc*v.x); a[5]=(short)f2bf(sc*v.y); a[6]=(short)f2bf(sc*v.z); a[7]=(short)f2bf(sc*v.w);
  return a;
}
__device__ __forceinline__ f4v mfma16(s8v a, s8v b, f4v c) {
  return __builtin_amdgcn_mfma_f32_16x16x32_bf16(a, b, c, 0, 0, 0);
}
// inputs pre-scaled to exp2 domain
__device__ __forceinline__ float sigm2(float x) {
  return __builtin_amdgcn_rcpf(1.f + __builtin_amdgcn_exp2f(-x));
}
__device__ __forceinline__ float tanh2(float x) {
  return __builtin_fmaf(2.f, __builtin_amdgcn_rcpf(1.f + __builtin_amdgcn_exp2f(-x)), -1.f);
}

__global__ void __launch_bounds__(BLK)
__attribute__((amdgpu_waves_per_eu(4, 4)))
prnn_kernel(
    const float* __restrict__ x, const float* __restrict__ w_ih,
    const float* __restrict__ w_hh, const float* __restrict__ b_ih,
    const float* __restrict__ b_hh, const float* __restrict__ w1,
    const float* __restrict__ b1, const float* __restrict__ w2,
    const float* __restrict__ b2, float* __restrict__ out) {

  __shared__ __align__(16) unsigned char lds_h[2][8192];       // 16 KB h B-frags (dbuf)
  __shared__ __align__(16) unsigned char lds_hid[2][8192];     // 16 KB hid B-frags (dbuf)
  __shared__ __align__(16) unsigned char lds_wA1[8*4*64*16];   // 32 KB w1 A-frags
  __shared__ __align__(16) unsigned char lds_w2f[4*64*16];     // 4 KB  w2 A-frags
  __shared__ __align__(16) float lds_xrz[64*4*4];              // 4 KB  xi r,z (*L2E)
  __shared__ __align__(16) float lds_xn[32*4*4];               // 2 KB  xi n (*2L2E)
  __shared__ __align__(16) float lds_b2[4];
  __shared__ unsigned lds_idx[32*8];                           // 1 KB
  __shared__ float lds_lp[8][32];                              // 1 KB

  const int tid = threadIdx.x;
  const int bbase = blockIdx.x * BT;
  const int lane = tid & 63;
  const int lg = lane >> 4, ln = lane & 15;
  const int w = __builtin_amdgcn_readfirstlane(tid >> 6);   // wave 0..7

  // ---- init: patch indices ----
  if (tid < 256) {
    int b = tid >> 3, ch = tid & 7;
    const float* xp = x + (size_t)(bbase + b) * 64 + ch * 8;
    float4 v0 = *(const float4*)xp, v1 = *(const float4*)(xp + 4);
    unsigned pk = ((v0.x!=0.f?1u:0u) | (v0.y!=0.f?2u:0u))
               | (((v0.z!=0.f?1u:0u) | (v0.w!=0.f?2u:0u)) << 8)
               | (((v1.x!=0.f?1u:0u) | (v1.y!=0.f?2u:0u)) << 16)
               | (((v1.z!=0.f?1u:0u) | (v1.w!=0.f?2u:0u)) << 24);
    lds_idx[b*8 + ch] = pk;
  }
  // ---- init: xi tables (prescaled) ----
  if (tid < 256) {                              // rows 0..255 (r,z) * L2E
    int j = tid;
    float base = b_ih[j] + b_hh[j];
    float wa = w_ih[2*j], wb = w_ih[2*j+1];
    int q = j >> 2, e = j & 3;
    #pragma unroll
    for (int v = 0; v < 4; ++v)
      lds_xrz[(q*4+v)*4 + e] = L2E * (base + ((v&1) ? wa : 0.f) + ((v&2) ? wb : 0.f));
  }
  if (tid < 128) {                              // rows 256..383 (n) * 2L2E
    int j2 = 256 + tid;
    float bn = b_ih[j2];
    float wan = w_ih[2*j2], wbn = w_ih[2*j2+1];
    int qn = tid >> 2, en = tid & 3;
    #pragma unroll
    for (int v = 0; v < 4; ++v)
      lds_xn[(qn*4+v)*4 + en] = (2.f*L2E) * (bn + ((v&1) ? wan : 0.f) + ((v&2) ? wbn : 0.f));
  }
  if (tid < 4) lds_b2[tid] = b2[tid];
  // ---- init: w1 A-frags, fragment order ----
  #pragma unroll
  for (int it = 0; it < 4; ++it) {
    int i = tid + it * BLK;                     // 0..2047
    int mt = i >> 8, ks = (i >> 6) & 3, l = i & 63;
    const float* src = w1 + (16*mt + (l & 15)) * 128 + ks*32 + (l >> 4)*8;
    *(s8v*)(lds_wA1 + ((mt*4 + ks)*64 + l)*16) = pack8s(1.f, *(const float4*)src, *(const float4*)(src+4));
  }
  // ---- init: w2 A-frags ----
  if (tid < 256) {
    int ks = tid >> 6, l = tid & 63;
    s8v fr;
    #pragma unroll
    for (int e = 0; e < 8; ++e) fr[e] = (short)0;
    if ((l & 15) < 4) {
      const float* src = w2 + (l & 15) * 128 + ks*32 + (l >> 4)*8;
      fr = pack8s(1.f, *(const float4*)src, *(const float4*)(src + 4));
    }
    *(s8v*)(lds_w2f + (ks*64 + l)*16) = fr;
  }

  // ---- register weights: w_hh A-frags (prescaled) ----
  s8v Ar[4], Az[4], An[4];
  {
    const int row = 16*w + ln;
    #pragma unroll
    for (int ks = 0; ks < 4; ++ks) {
      const float* s0 = w_hh + row*128 + ks*32 + lg*8;
      Ar[ks] = pack8s(L2E, *(const float4*)s0, *(const float4*)(s0 + 4));
      const float* s1 = s0 + 128*128;
      Az[ks] = pack8s(L2E, *(const float4*)s1, *(const float4*)(s1 + 4));
      const float* s2 = s0 + 256*128;
      An[ks] = pack8s(2.f*L2E, *(const float4*)s2, *(const float4*)(s2 + 4));
    }
  }
  // ---- register biases ----
  const int q = 4*w + lg;
  f4v bhnr, b1i;
  {
    const f4v bh = *(const f4v*)(b_hh + 256 + q*4);
    bhnr[0]=(2.f*L2E)*bh[0]; bhnr[1]=(2.f*L2E)*bh[1]; bhnr[2]=(2.f*L2E)*bh[2]; bhnr[3]=(2.f*L2E)*bh[3];
    b1i = *(const f4v*)(b1 + q*4);
  }

  __syncthreads();

  // ---- per-lane packed patch history (cols ln, 16+ln) ----
  unsigned pk0a=0, pk0b=0, pk1a=0, pk1b=0;
  #pragma unroll
  for (int w8 = 0; w8 < 4; ++w8) {
    unsigned u = lds_idx[ln*8 + w8];
    pk0a |= (((u&3u) | ((u>>6)&0xCu) | ((u>>12)&0x30u) | ((u>>18)&0xC0u)) << (8*w8));
    unsigned u2 = lds_idx[(16+ln)*8 + w8];
    pk1a |= (((u2&3u) | ((u2>>6)&0xCu) | ((u2>>12)&0x30u) | ((u2>>18)&0xC0u)) << (8*w8));
  }
  #pragma unroll
  for (int w8 = 4; w8 < 8; ++w8) {
    unsigned u = lds_idx[ln*8 + w8];
    pk0b |= (((u&3u) | ((u>>6)&0xCu) | ((u>>12)&0x30u) | ((u>>18)&0xC0u)) << (8*(w8-4)));
    unsigned u2 = lds_idx[(16+ln)*8 + w8];
    pk1b |= (((u2&3u) | ((u2>>6)&0xCu) | ((u2>>12)&0x30u) | ((u2>>18)&0xC0u)) << (8*(w8-4)));
  }

  const unsigned wroff = (unsigned)((((w>>1)*128) + 16*(2*(w&1) + (lg>>1)) + ln)*16 + 8*(lg&1));

  s8v Bf[4][2];
  #pragma unroll
  for (int ks = 0; ks < 4; ++ks)
    #pragma unroll
    for (int nt = 0; nt < 2; ++nt)
      #pragma unroll
      for (int e = 0; e < 8; ++e) Bf[ks][nt][e] = (short)0;
  f4v hfr[2];
  hfr[0][0]=0.f; hfr[0][1]=0.f; hfr[0][2]=0.f; hfr[0][3]=0.f;
  hfr[1] = hfr[0];
  float lp0 = 0.f, lp1 = 0.f;
  int pv0 = 0, pv1 = 0;

  // P5 body: logits + log-softmax gather for step u (one nt half per wave pair)
  auto do_p5 = [&](int u, int uslot) {
    const int ua = u & 7;
    const bool d0 = (w == ua), d1 = (w == (ua ^ 4));
    if (d0 | d1) {
      const int ntx = d1 ? 1 : 0;
      f4v la;
      if (lg == 0) la = *(const f4v*)lds_b2;
      else { la[0]=0.f; la[1]=0.f; la[2]=0.f; la[3]=0.f; }
      #pragma unroll
      for (int ks = 0; ks < 4; ++ks) {
        const s8v W2f = *(const s8v*)(lds_w2f + (ks*64 + lane)*16);
        const s8v Bh  = *(const s8v*)(&lds_hid[uslot][((ks*2 + ntx)*64 + lane)*16]);
        la = mfma16(W2f, Bh, la);
      }
      if (lg == 0) {
        const unsigned hsel = ntx ? ((u & 16) ? pk1b : pk1a) : ((u & 16) ? pk0b : pk0a);
        const int ic = (int)((hsel >> ((2*u) & 31)) & 3);
        float l0=la[0], l1=la[1], l2=la[2], l3=la[3];
        float m = fmaxf(fmaxf(l0, l1), fmaxf(l2, l3));
        float s = __builtin_amdgcn_exp2f((l0-m)*L2E) + __builtin_amdgcn_exp2f((l1-m)*L2E)
                + __builtin_amdgcn_exp2f((l2-m)*L2E) + __builtin_amdgcn_exp2f((l3-m)*L2E);
        float sel = (ic == 0) ? l0 : (ic == 1) ? l1 : (ic == 2) ? l2 : l3;
        float v = (sel - m) - __builtin_amdgcn_logf(s) * LN2;
        if (ntx) lp1 += v; else lp0 += v;
      }
    }
  };

  for (int tb = 0; tb < NSTEP; tb += 8) {
    #pragma unroll
    for (int k = 0; k < 8; ++k) {
      const int t = tb + k;
      const int slot = t & 1;
      // ---- P1: gate MFMAs (C-init = prescaled xi) + gates + h write ----
      #pragma unroll
      for (int nt = 0; nt < 2; ++nt) {
        const int var = nt ? pv1 : pv0;
        f4v aR = *(const f4v*)&lds_xrz[(q*4 + var)*4];
        f4v aZ = *(const f4v*)&lds_xrz[((q+32)*4 + var)*4];
        f4v aN = bhnr;
        #pragma unroll
        for (int ks = 0; ks < 4; ++ks) {
          aR = mfma16(Ar[ks], Bf[ks][nt], aR);
          aZ = mfma16(Az[ks], Bf[ks][nt], aZ);
          aN = mfma16(An[ks], Bf[ks][nt], aN);
        }
        const f4v xnv = *(const f4v*)&lds_xn[(q*4 + var)*4];
        f4v hn;
        #pragma unroll
        for (int r = 0; r < 4; ++r) {
          float R  = sigm2(aR[r]);
          float Z  = sigm2(aZ[r]);
          float Ng = tanh2(__builtin_fmaf(R, aN[r], xnv[r]));
          hn[r] = __builtin_fmaf(Z, hfr[nt][r] - Ng, Ng);
        }
        hfr[nt] = hn;
        uint2 wv;
        wv.x = pkbf2(hn[0], hn[1]);
        wv.y = pkbf2(hn[2], hn[3]);
        *(uint2*)(&lds_h[slot][wroff + (unsigned)(nt*1024)]) = wv;
      }
      __syncthreads();                           // B1: h(t) complete
      // ---- read Bf (feeds P4 now and P1 of t+1) ----
      #pragma unroll
      for (int ks = 0; ks < 4; ++ks)
        #pragma unroll
        for (int nt = 0; nt < 2; ++nt)
          Bf[ks][nt] = *(const s8v*)(&lds_h[slot][((ks*2 + nt)*64 + lane)*16]);
      // ---- P4: hid = relu(W1 h + b1) -> lds_hid[slot] ----
      f4v hc0 = b1i, hc1 = b1i;
      #pragma unroll
      for (int ks = 0; ks < 4; ++ks) {
        const s8v wf = *(const s8v*)(lds_wA1 + ((w*4 + ks)*64 + lane)*16);
        hc0 = mfma16(wf, Bf[ks][0], hc0);
        hc1 = mfma16(wf, Bf[ks][1], hc1);
      }
      {
        uint2 wv;
        wv.x = pkbf2(fmaxf(hc0[0],0.f), fmaxf(hc0[1],0.f));
        wv.y = pkbf2(fmaxf(hc0[2],0.f), fmaxf(hc0[3],0.f));
        *(uint2*)(&lds_hid[slot][wroff]) = wv;
        wv.x = pkbf2(fmaxf(hc1[0],0.f), fmaxf(hc1[1],0.f));
        wv.y = pkbf2(fmaxf(hc1[2],0.f), fmaxf(hc1[3],0.f));
        *(uint2*)(&lds_hid[slot][wroff + 1024u]) = wv;
      }
      // ---- P5 for step t-1 (reads hid[slot^1], synced by B1 above) ----
      if (t > 0) do_p5(t - 1, slot ^ 1);
      // ---- advance teacher-forcing input ----
      {
        const unsigned g0 = (t & 16) ? pk0b : pk0a;
        const unsigned g1 = (t & 16) ? pk1b : pk1a;
        const int sh = (2*t) & 31;
        pv0 = (int)((g0 >> sh) & 3);
        pv1 = (int)((g1 >> sh) & 3);
      }
    }
  }

  // ---- epilogue: P5 for t=31 ----
  __syncthreads();
  do_p5(NSTEP - 1, (NSTEP - 1) & 1);

  // ---- cross-wave logp reduction ----
  if (lg == 0) { lds_lp[w][ln] = lp0; lds_lp[w][16 + ln] = lp1; }
  __syncthreads();
  if (tid < 32) {
    float s = 0.f;
    #pragma unroll
    for (int ww = 0; ww < 8; ++ww) s += lds_lp[ww][tid];
    out[bbase + tid] = s;
  }
}

extern "C" void kernel_launch(void* const* d_in, const int* in_sizes, int n_in,
                              void* d_out, int out_size, void* d_ws, size_t ws_size,
                              hipStream_t stream) {
  const float* x    = (const float*)d_in[0];
  const float* w_ih = (const float*)d_in[1];
  const float* w_hh = (const float*)d_in[2];
  const float* b_ih = (const float*)d_in[3];
  const float* b_hh = (const float*)d_in[4];
  const float* w1   = (const float*)d_in[5];
  const float* b1   = (const float*)d_in[6];
  const float* w2   = (const float*)d_in[7];
  const float* b2   = (const float*)d_in[8];
  float* out = (float*)d_out;
  int B = in_sizes[0] / 64;          // 16384
  int grid = B / BT;                 // 512
  prnn_kernel<<<grid, BLK, 0, stream>>>(x, w_ih, w_hh, b_ih, b_hh, w1, b1, w2, b2, out);
}